// Round 3
// baseline (2586.185 us; speedup 1.0000x reference)
//
#include <hip/hip_runtime.h>
#include <hip/hip_bf16.h>

#define N_NODES   50000
#define N_EDGES   800000
#define IN_DIM    128
#define EDGE_DIM  32
#define HIDDEN    128
#define NUM_LAYERS 3
#define BN_EPS    1e-5f
#define RES_SCALE 0.1f

typedef unsigned int u32;

// ---------------- copy x -> h ; zero deg ----------------
__global__ __launch_bounds__(256) void init_kernel(const float* __restrict__ x,
                                                   float* __restrict__ h,
                                                   u32* __restrict__ deg) {
    int idx = blockIdx.x * 256 + threadIdx.x;
    if (idx < N_NODES * HIDDEN) h[idx] = x[idx];
    if (idx < N_NODES) deg[idx] = 0u;
}

// ---------------- degree histogram ----------------
__global__ __launch_bounds__(256) void hist_kernel(const int* __restrict__ ei,
                                                   u32* __restrict__ deg) {
    int e = blockIdx.x * 256 + threadIdx.x;
    if (e < N_EDGES) atomicAdd(&deg[ei[N_EDGES + e]], 1u);
}

// ---------------- exclusive scan (single block, 1024 threads) ----------------
#define SCAN_THREADS 1024
__global__ __launch_bounds__(SCAN_THREADS) void scan_kernel(
    const u32* __restrict__ deg, u32* __restrict__ off, u32* __restrict__ cursor) {
    __shared__ u32 part[SCAN_THREADS];
    int t = threadIdx.x;
    const int CHUNK = (N_NODES + SCAN_THREADS - 1) / SCAN_THREADS;  // 49
    int start = t * CHUNK;
    int end = start + CHUNK; if (end > N_NODES) end = N_NODES;
    u32 s = 0;
    for (int i = start; i < end; i++) s += deg[i];
    part[t] = s;
    __syncthreads();
    for (int d = 1; d < SCAN_THREADS; d <<= 1) {
        u32 v = (t >= d) ? part[t - d] : 0u;
        __syncthreads();
        part[t] += v;
        __syncthreads();
    }
    u32 run = (t == 0) ? 0u : part[t - 1];
    for (int i = start; i < end; i++) {
        u32 d = deg[i];
        off[i] = run;
        cursor[i] = run;
        run += d;
    }
    if (t == SCAN_THREADS - 1) off[N_NODES] = run;
}

// ---------------- scatter edges into CSR order ----------------
__global__ __launch_bounds__(256) void scatter_kernel(const int* __restrict__ ei,
                                                      u32* __restrict__ cursor,
                                                      int* __restrict__ ssrc,
                                                      int* __restrict__ seid) {
    int e = blockIdx.x * 256 + threadIdx.x;
    if (e < N_EDGES) {
        int dst = ei[N_EDGES + e];
        u32 pos = atomicAdd(&cursor[dst], 1u);
        ssrc[pos] = ei[e];
        seid[pos] = e;
    }
}

// ---------------- CSR aggregation: z[n] = h[n] + sum_e relu(h[src]+ea@We+be) ----
__global__ __launch_bounds__(256) void agg_csr_kernel(
    const float* __restrict__ h, const float* __restrict__ ea,
    const int* __restrict__ ssrc, const int* __restrict__ seid,
    const u32* __restrict__ off, const float* __restrict__ We,
    const float* __restrict__ be, float* __restrict__ z) {
    int t = threadIdx.x;
    int f = t & 127;
    int slot = t >> 7;
    float wcol[EDGE_DIM];
#pragma unroll
    for (int k = 0; k < EDGE_DIM; k++) wcol[k] = We[k * HIDDEN + f];
    float bias = be[f];
    int nslots = gridDim.x * 2;
    for (int n = blockIdx.x * 2 + slot; n < N_NODES; n += nslots) {
        u32 e0 = off[n], e1 = off[n + 1];
        float acc = 0.f;
        for (u32 e = e0; e < e1; e++) {
            int src = ssrc[e];
            int eid = seid[e];
            const float4* eap = (const float4*)(ea + (size_t)eid * EDGE_DIM);
            float m = bias;
#pragma unroll
            for (int q = 0; q < 8; q++) {
                float4 p = eap[q];
                m = fmaf(p.x, wcol[q * 4 + 0], m);
                m = fmaf(p.y, wcol[q * 4 + 1], m);
                m = fmaf(p.z, wcol[q * 4 + 2], m);
                m = fmaf(p.w, wcol[q * 4 + 3], m);
            }
            m += h[(size_t)src * HIDDEN + f];
            acc += fmaxf(m, 0.f);
        }
        z[(size_t)n * HIDDEN + f] = h[(size_t)n * HIDDEN + f] + acc;
    }
}

// ---------------- zero stats ----------------
__global__ __launch_bounds__(256) void zero_stats_kernel(float* __restrict__ stats) {
    stats[threadIdx.x] = 0.f;
}

// ---------------- 128-wide node GEMM, K-tiled, in-place safe ----------------
template <int RELU, int STATS>
__global__ __launch_bounds__(256) void gemm128_kernel(
    const float* __restrict__ in, const float* __restrict__ W,
    const float* __restrict__ bias, float* __restrict__ out,
    float* __restrict__ stats) {
    __shared__ float Wt[32][HIDDEN];        // 16 KB
    __shared__ float zt[32][33];            // 4.3 KB
    __shared__ float red[8][32][4][2];      // 8 KB
    int t = threadIdx.x;
    int base = blockIdx.x * 32;
    int ng = t >> 5, fg = t & 31;

    float acc[4][4];
#pragma unroll
    for (int i = 0; i < 4; i++)
#pragma unroll
        for (int j = 0; j < 4; j++) acc[i][j] = 0.f;

    for (int kt = 0; kt < 4; kt++) {
        int k0 = kt * 32;
        for (int i = t; i < 32 * HIDDEN; i += 256) {
            int kk = i >> 7, ff = i & 127;
            Wt[kk][ff] = W[(size_t)(k0 + kk) * HIDDEN + ff];
        }
        for (int i = t; i < 32 * 32; i += 256) {
            int n = i >> 5, kk = i & 31;
            int gn = base + n;
            zt[n][kk] = (gn < N_NODES) ? in[(size_t)gn * HIDDEN + k0 + kk] : 0.f;
        }
        __syncthreads();
#pragma unroll 4
        for (int kk = 0; kk < 32; kk++) {
            float zv[4];
#pragma unroll
            for (int i = 0; i < 4; i++) zv[i] = zt[ng * 4 + i][kk];
            float4 wv = *(const float4*)&Wt[kk][fg * 4];
#pragma unroll
            for (int i = 0; i < 4; i++) {
                acc[i][0] = fmaf(zv[i], wv.x, acc[i][0]);
                acc[i][1] = fmaf(zv[i], wv.y, acc[i][1]);
                acc[i][2] = fmaf(zv[i], wv.z, acc[i][2]);
                acc[i][3] = fmaf(zv[i], wv.w, acc[i][3]);
            }
        }
        __syncthreads();
    }

    float bv[4];
#pragma unroll
    for (int j = 0; j < 4; j++) bv[j] = bias[fg * 4 + j];
#pragma unroll
    for (int i = 0; i < 4; i++) {
        int gn = base + ng * 4 + i;
#pragma unroll
        for (int j = 0; j < 4; j++) {
            float v = acc[i][j] + bv[j];
            if (RELU) v = fmaxf(v, 0.f);
            acc[i][j] = v;
        }
        if (gn < N_NODES) {
            float4 st = make_float4(acc[i][0], acc[i][1], acc[i][2], acc[i][3]);
            *(float4*)&out[(size_t)gn * HIDDEN + fg * 4] = st;
        }
    }

    if (STATS) {
        float s[4] = {0.f, 0.f, 0.f, 0.f}, sq[4] = {0.f, 0.f, 0.f, 0.f};
#pragma unroll
        for (int i = 0; i < 4; i++) {
            int gn = base + ng * 4 + i;
            if (gn < N_NODES) {
#pragma unroll
                for (int j = 0; j < 4; j++) {
                    s[j] += acc[i][j];
                    sq[j] = fmaf(acc[i][j], acc[i][j], sq[j]);
                }
            }
        }
#pragma unroll
        for (int j = 0; j < 4; j++) {
            red[ng][fg][j][0] = s[j];
            red[ng][fg][j][1] = sq[j];
        }
        __syncthreads();
        if (t < HIDDEN) {
            int ffg = t >> 2, jj = t & 3;
            float ts = 0.f, tq = 0.f;
            for (int g = 0; g < 8; g++) {
                ts += red[g][ffg][jj][0];
                tq += red[g][ffg][jj][1];
            }
            unsafeAtomicAdd(&stats[ffg * 4 + jj], ts);
            unsafeAtomicAdd(&stats[HIDDEN + ffg * 4 + jj], tq);
        }
    }
}

// ---------------- batchnorm + relu + residual ----------------
__global__ __launch_bounds__(256) void bn_kernel(
    const float* __restrict__ z2, const float* __restrict__ stats,
    const float* __restrict__ gamma, const float* __restrict__ beta,
    float* __restrict__ h, float* __restrict__ out, int write_out) {
    int idx = blockIdx.x * 256 + threadIdx.x;
    if (idx >= N_NODES * HIDDEN) return;
    int f = idx & 127;
    const float inv_n = 1.0f / (float)N_NODES;
    float mu = stats[f] * inv_n;
    float var = stats[HIDDEN + f] * inv_n - mu * mu;
    float inv = rsqrtf(var + BN_EPS);
    float z = (z2[idx] - mu) * inv * gamma[f] + beta[f];
    z = fmaxf(z, 0.f);
    float hn = fmaf(RES_SCALE, h[idx], z);
    h[idx] = hn;
    if (write_out) out[idx] = hn;
}

extern "C" void kernel_launch(void* const* d_in, const int* in_sizes, int n_in,
                              void* d_out, int out_size, void* d_ws, size_t ws_size,
                              hipStream_t stream) {
    const float* x     = (const float*)d_in[0];
    const int*   ei    = (const int*)d_in[1];
    const float* ea    = (const float*)d_in[2];
    const float* We    = (const float*)d_in[3];
    const float* be    = (const float*)d_in[4];
    const float* W1    = (const float*)d_in[5];
    const float* b1    = (const float*)d_in[6];
    const float* W2    = (const float*)d_in[7];
    const float* b2    = (const float*)d_in[8];
    const float* gamma = (const float*)d_in[9];
    const float* beta  = (const float*)d_in[10];
    float* out = (float*)d_out;

    char* ws = (char*)d_ws;
    const size_t NH = (size_t)N_NODES * HIDDEN;
    float* h     = (float*)ws;                        ws += NH * 4;
    float* z     = (float*)ws;                        ws += NH * 4;   // z -> t1 -> z2 (in-place GEMMs)
    float* stats = (float*)ws;                        ws += 256 * 4;
    u32*   deg   = (u32*)ws;                          ws += (size_t)N_NODES * 4;
    u32*   off   = (u32*)ws;                          ws += (size_t)(N_NODES + 1) * 4;
    u32*   cursor= (u32*)ws;                          ws += (size_t)N_NODES * 4;
    int*   ssrc  = (int*)ws;                          ws += (size_t)N_EDGES * 4;
    int*   seid  = (int*)ws;                          ws += (size_t)N_EDGES * 4;

    const int nh_blocks = (N_NODES * HIDDEN + 255) / 256;   // 25000
    const int e_blocks  = (N_EDGES + 255) / 256;            // 3125
    const int g_blocks  = (N_NODES + 31) / 32;              // 1563

    // CSR build (once per call)
    init_kernel<<<nh_blocks, 256, 0, stream>>>(x, h, deg);
    hist_kernel<<<e_blocks, 256, 0, stream>>>(ei, deg);
    scan_kernel<<<1, SCAN_THREADS, 0, stream>>>(deg, off, cursor);
    scatter_kernel<<<e_blocks, 256, 0, stream>>>(ei, cursor, ssrc, seid);

    for (int l = 0; l < NUM_LAYERS; l++) {
        agg_csr_kernel<<<8192, 256, 0, stream>>>(
            h, ea, ssrc, seid, off,
            We + (size_t)l * EDGE_DIM * HIDDEN, be + (size_t)l * HIDDEN, z);
        gemm128_kernel<1, 0><<<g_blocks, 256, 0, stream>>>(
            z, W1 + (size_t)l * HIDDEN * HIDDEN, b1 + (size_t)l * HIDDEN, z, nullptr);
        zero_stats_kernel<<<1, 256, 0, stream>>>(stats);
        gemm128_kernel<0, 1><<<g_blocks, 256, 0, stream>>>(
            z, W2 + (size_t)l * HIDDEN * HIDDEN, b2 + (size_t)l * HIDDEN, z, stats);
        bn_kernel<<<nh_blocks, 256, 0, stream>>>(
            z, stats, gamma + (size_t)l * HIDDEN, beta + (size_t)l * HIDDEN,
            h, out, (l == NUM_LAYERS - 1) ? 1 : 0);
    }
}

// Round 4
// 1497.793 us; speedup vs baseline: 1.7267x; 1.7267x over previous
//
#include <hip/hip_runtime.h>
#include <hip/hip_bf16.h>

#define N_NODES   50000
#define N_EDGES   800000
#define IN_DIM    128
#define EDGE_DIM  32
#define HIDDEN    128
#define NUM_LAYERS 3
#define BN_EPS    1e-5f
#define RES_SCALE 0.1f

typedef unsigned int   u32;
typedef unsigned short u16;

__device__ __forceinline__ float bf2f(u32 v16) {
    union { u32 u; float f; } c; c.u = v16 << 16; return c.f;
}
__device__ __forceinline__ float bf2f_hi(u32 dword) {
    union { u32 u; float f; } c; c.u = dword & 0xFFFF0000u; return c.f;
}

// ---------------- copy x -> h ; zero deg ----------------
__global__ __launch_bounds__(256) void init_kernel(const float* __restrict__ x,
                                                   float* __restrict__ h,
                                                   u32* __restrict__ deg) {
    int idx = blockIdx.x * 256 + threadIdx.x;
    if (idx < N_NODES * HIDDEN) h[idx] = x[idx];
    if (idx < N_NODES) deg[idx] = 0u;
}

// ---------------- degree histogram ----------------
__global__ __launch_bounds__(256) void hist_kernel(const int* __restrict__ ei,
                                                   u32* __restrict__ deg) {
    int e = blockIdx.x * 256 + threadIdx.x;
    if (e < N_EDGES) atomicAdd(&deg[ei[N_EDGES + e]], 1u);
}

// ---------------- exclusive scan (single block) ----------------
#define SCAN_THREADS 1024
__global__ __launch_bounds__(SCAN_THREADS) void scan_kernel(
    const u32* __restrict__ deg, u32* __restrict__ off, u32* __restrict__ cursor) {
    __shared__ u32 part[SCAN_THREADS];
    int t = threadIdx.x;
    const int CHUNK = (N_NODES + SCAN_THREADS - 1) / SCAN_THREADS;  // 49
    int start = t * CHUNK;
    int end = start + CHUNK; if (end > N_NODES) end = N_NODES;
    u32 s = 0;
    for (int i = start; i < end; i++) s += deg[i];
    part[t] = s;
    __syncthreads();
    for (int d = 1; d < SCAN_THREADS; d <<= 1) {
        u32 v = (t >= d) ? part[t - d] : 0u;
        __syncthreads();
        part[t] += v;
        __syncthreads();
    }
    u32 run = (t == 0) ? 0u : part[t - 1];
    for (int i = start; i < end; i++) {
        u32 d = deg[i];
        off[i] = run;
        cursor[i] = run;
        run += d;
    }
    if (t == SCAN_THREADS - 1) off[N_NODES] = run;
}

// ---------------- scatter edges into CSR order ----------------
__global__ __launch_bounds__(256) void scatter_kernel(const int* __restrict__ ei,
                                                      u32* __restrict__ cursor,
                                                      int* __restrict__ ssrc,
                                                      int* __restrict__ seid) {
    int e = blockIdx.x * 256 + threadIdx.x;
    if (e < N_EDGES) {
        int dst = ei[N_EDGES + e];
        u32 pos = atomicAdd(&cursor[dst], 1u);
        ssrc[pos] = ei[e];
        seid[pos] = e;
    }
}

// ---------------- permute edge_attr into CSR order, cast bf16 ----------------
__global__ __launch_bounds__(256) void perm_ea_kernel(const float* __restrict__ ea,
                                                      const int* __restrict__ seid,
                                                      u16* __restrict__ ea_perm) {
    int idx = blockIdx.x * 256 + threadIdx.x;
    if (idx < N_EDGES * EDGE_DIM) {
        int pos = idx >> 5, col = idx & 31;
        int eid = seid[pos];
        float v = ea[(size_t)eid * EDGE_DIM + col];
        ((__hip_bfloat16*)ea_perm)[idx] = __float2bfloat16(v);
    }
}

// bf16 row (4 x uint4 = 32 bf16) dot wcol[32], two independent chains
__device__ __forceinline__ float edot_bf16(const uint4* __restrict__ p,
                                           const float* __restrict__ wcol) {
    float ma = 0.f, mb = 0.f;
#pragma unroll
    for (int q = 0; q < 4; q++) {
        uint4 d = p[q];
        u32 a[4] = {d.x, d.y, d.z, d.w};
#pragma unroll
        for (int j = 0; j < 4; j++) {
            float lo = bf2f(a[j] & 0xFFFFu);
            float hi = bf2f_hi(a[j]);
            if (j & 1) {
                mb = fmaf(lo, wcol[q * 8 + j * 2 + 0], mb);
                mb = fmaf(hi, wcol[q * 8 + j * 2 + 1], mb);
            } else {
                ma = fmaf(lo, wcol[q * 8 + j * 2 + 0], ma);
                ma = fmaf(hi, wcol[q * 8 + j * 2 + 1], ma);
            }
        }
    }
    return ma + mb;
}

// fp32 row (8 x float4) dot wcol[32], two independent chains
__device__ __forceinline__ float edot_f32(const float4* __restrict__ p,
                                          const float* __restrict__ wcol) {
    float ma = 0.f, mb = 0.f;
#pragma unroll
    for (int q = 0; q < 8; q++) {
        float4 v = p[q];
        if (q & 1) {
            mb = fmaf(v.x, wcol[q * 4 + 0], mb);
            mb = fmaf(v.y, wcol[q * 4 + 1], mb);
            mb = fmaf(v.z, wcol[q * 4 + 2], mb);
            mb = fmaf(v.w, wcol[q * 4 + 3], mb);
        } else {
            ma = fmaf(v.x, wcol[q * 4 + 0], ma);
            ma = fmaf(v.y, wcol[q * 4 + 1], ma);
            ma = fmaf(v.z, wcol[q * 4 + 2], ma);
            ma = fmaf(v.w, wcol[q * 4 + 3], ma);
        }
    }
    return ma + mb;
}

// ---------------- CSR aggregation (permuted bf16 ea, contiguous) ----------------
// z[n] = h[n] + sum_{e in [off[n],off[n+1])} relu(h[ssrc[e]] + ea_perm[e]@We + be)
__global__ __launch_bounds__(256) void agg_perm_kernel(
    const float* __restrict__ h, const u16* __restrict__ ea_perm,
    const int* __restrict__ ssrc, const u32* __restrict__ off,
    const float* __restrict__ We, const float* __restrict__ be,
    float* __restrict__ z) {
    int t = threadIdx.x;
    int f = t & 127;
    int slot = t >> 7;
    float wcol[EDGE_DIM];
#pragma unroll
    for (int k = 0; k < EDGE_DIM; k++) wcol[k] = We[k * HIDDEN + f];
    float bias = be[f];
    int nslots = gridDim.x * 2;
    for (int n = blockIdx.x * 2 + slot; n < N_NODES; n += nslots) {
        u32 e0 = off[n], e1 = off[n + 1];
        float acc0 = 0.f, acc1 = 0.f;
        u32 e = e0;
        for (; e + 2 <= e1; e += 2) {
            int s0 = ssrc[e], s1 = ssrc[e + 1];
            const uint4* p0 = (const uint4*)(ea_perm + (size_t)e * EDGE_DIM);
            float h0 = h[(size_t)s0 * HIDDEN + f];
            float h1 = h[(size_t)s1 * HIDDEN + f];
            float m0 = edot_bf16(p0, wcol) + bias + h0;
            float m1 = edot_bf16(p0 + 4, wcol) + bias + h1;
            acc0 += fmaxf(m0, 0.f);
            acc1 += fmaxf(m1, 0.f);
        }
        if (e < e1) {
            int s0 = ssrc[e];
            const uint4* p0 = (const uint4*)(ea_perm + (size_t)e * EDGE_DIM);
            float m0 = edot_bf16(p0, wcol) + bias + h[(size_t)s0 * HIDDEN + f];
            acc0 += fmaxf(m0, 0.f);
        }
        z[(size_t)n * HIDDEN + f] = h[(size_t)n * HIDDEN + f] + acc0 + acc1;
    }
}

// ---------------- fallback: CSR aggregation with fp32 ea indirection ----------------
__global__ __launch_bounds__(256) void agg_ind_kernel(
    const float* __restrict__ h, const float* __restrict__ ea,
    const int* __restrict__ ssrc, const int* __restrict__ seid,
    const u32* __restrict__ off, const float* __restrict__ We,
    const float* __restrict__ be, float* __restrict__ z) {
    int t = threadIdx.x;
    int f = t & 127;
    int slot = t >> 7;
    float wcol[EDGE_DIM];
#pragma unroll
    for (int k = 0; k < EDGE_DIM; k++) wcol[k] = We[k * HIDDEN + f];
    float bias = be[f];
    int nslots = gridDim.x * 2;
    for (int n = blockIdx.x * 2 + slot; n < N_NODES; n += nslots) {
        u32 e0 = off[n], e1 = off[n + 1];
        float acc0 = 0.f, acc1 = 0.f;
        u32 e = e0;
        for (; e + 2 <= e1; e += 2) {
            int s0 = ssrc[e], s1 = ssrc[e + 1];
            int i0 = seid[e], i1 = seid[e + 1];
            const float4* p0 = (const float4*)(ea + (size_t)i0 * EDGE_DIM);
            const float4* p1 = (const float4*)(ea + (size_t)i1 * EDGE_DIM);
            float h0 = h[(size_t)s0 * HIDDEN + f];
            float h1 = h[(size_t)s1 * HIDDEN + f];
            float m0 = edot_f32(p0, wcol) + bias + h0;
            float m1 = edot_f32(p1, wcol) + bias + h1;
            acc0 += fmaxf(m0, 0.f);
            acc1 += fmaxf(m1, 0.f);
        }
        if (e < e1) {
            int s0 = ssrc[e];
            int i0 = seid[e];
            const float4* p0 = (const float4*)(ea + (size_t)i0 * EDGE_DIM);
            float m0 = edot_f32(p0, wcol) + bias + h[(size_t)s0 * HIDDEN + f];
            acc0 += fmaxf(m0, 0.f);
        }
        z[(size_t)n * HIDDEN + f] = h[(size_t)n * HIDDEN + f] + acc0 + acc1;
    }
}

// ---------------- zero stats ----------------
__global__ __launch_bounds__(256) void zero_stats_kernel(float* __restrict__ stats) {
    stats[threadIdx.x] = 0.f;
}

// ---------------- 128-wide node GEMM, K-tiled, in-place safe ----------------
template <int RELU, int STATS>
__global__ __launch_bounds__(256) void gemm128_kernel(
    const float* __restrict__ in, const float* __restrict__ W,
    const float* __restrict__ bias, float* __restrict__ out,
    float* __restrict__ stats) {
    __shared__ float Wt[32][HIDDEN];        // 16 KB
    __shared__ float zt[32][33];            // 4.3 KB
    __shared__ float red[8][32][4][2];      // 8 KB
    int t = threadIdx.x;
    int base = blockIdx.x * 32;
    int ng = t >> 5, fg = t & 31;

    float acc[4][4];
#pragma unroll
    for (int i = 0; i < 4; i++)
#pragma unroll
        for (int j = 0; j < 4; j++) acc[i][j] = 0.f;

    for (int kt = 0; kt < 4; kt++) {
        int k0 = kt * 32;
        for (int i = t; i < 32 * HIDDEN; i += 256) {
            int kk = i >> 7, ff = i & 127;
            Wt[kk][ff] = W[(size_t)(k0 + kk) * HIDDEN + ff];
        }
        for (int i = t; i < 32 * 32; i += 256) {
            int n = i >> 5, kk = i & 31;
            int gn = base + n;
            zt[n][kk] = (gn < N_NODES) ? in[(size_t)gn * HIDDEN + k0 + kk] : 0.f;
        }
        __syncthreads();
#pragma unroll 4
        for (int kk = 0; kk < 32; kk++) {
            float zv[4];
#pragma unroll
            for (int i = 0; i < 4; i++) zv[i] = zt[ng * 4 + i][kk];
            float4 wv = *(const float4*)&Wt[kk][fg * 4];
#pragma unroll
            for (int i = 0; i < 4; i++) {
                acc[i][0] = fmaf(zv[i], wv.x, acc[i][0]);
                acc[i][1] = fmaf(zv[i], wv.y, acc[i][1]);
                acc[i][2] = fmaf(zv[i], wv.z, acc[i][2]);
                acc[i][3] = fmaf(zv[i], wv.w, acc[i][3]);
            }
        }
        __syncthreads();
    }

    float bv[4];
#pragma unroll
    for (int j = 0; j < 4; j++) bv[j] = bias[fg * 4 + j];
#pragma unroll
    for (int i = 0; i < 4; i++) {
        int gn = base + ng * 4 + i;
#pragma unroll
        for (int j = 0; j < 4; j++) {
            float v = acc[i][j] + bv[j];
            if (RELU) v = fmaxf(v, 0.f);
            acc[i][j] = v;
        }
        if (gn < N_NODES) {
            float4 st = make_float4(acc[i][0], acc[i][1], acc[i][2], acc[i][3]);
            *(float4*)&out[(size_t)gn * HIDDEN + fg * 4] = st;
        }
    }

    if (STATS) {
        float s[4] = {0.f, 0.f, 0.f, 0.f}, sq[4] = {0.f, 0.f, 0.f, 0.f};
#pragma unroll
        for (int i = 0; i < 4; i++) {
            int gn = base + ng * 4 + i;
            if (gn < N_NODES) {
#pragma unroll
                for (int j = 0; j < 4; j++) {
                    s[j] += acc[i][j];
                    sq[j] = fmaf(acc[i][j], acc[i][j], sq[j]);
                }
            }
        }
#pragma unroll
        for (int j = 0; j < 4; j++) {
            red[ng][fg][j][0] = s[j];
            red[ng][fg][j][1] = sq[j];
        }
        __syncthreads();
        if (t < HIDDEN) {
            int ffg = t >> 2, jj = t & 3;
            float ts = 0.f, tq = 0.f;
            for (int g = 0; g < 8; g++) {
                ts += red[g][ffg][jj][0];
                tq += red[g][ffg][jj][1];
            }
            unsafeAtomicAdd(&stats[ffg * 4 + jj], ts);
            unsafeAtomicAdd(&stats[HIDDEN + ffg * 4 + jj], tq);
        }
    }
}

// ---------------- batchnorm + relu + residual ----------------
__global__ __launch_bounds__(256) void bn_kernel(
    const float* __restrict__ z2, const float* __restrict__ stats,
    const float* __restrict__ gamma, const float* __restrict__ beta,
    float* __restrict__ h, float* __restrict__ out, int write_out) {
    int idx = blockIdx.x * 256 + threadIdx.x;
    if (idx >= N_NODES * HIDDEN) return;
    int f = idx & 127;
    const float inv_n = 1.0f / (float)N_NODES;
    float mu = stats[f] * inv_n;
    float var = stats[HIDDEN + f] * inv_n - mu * mu;
    float inv = rsqrtf(var + BN_EPS);
    float z = (z2[idx] - mu) * inv * gamma[f] + beta[f];
    z = fmaxf(z, 0.f);
    float hn = fmaf(RES_SCALE, h[idx], z);
    h[idx] = hn;
    if (write_out) out[idx] = hn;
}

extern "C" void kernel_launch(void* const* d_in, const int* in_sizes, int n_in,
                              void* d_out, int out_size, void* d_ws, size_t ws_size,
                              hipStream_t stream) {
    const float* x     = (const float*)d_in[0];
    const int*   ei    = (const int*)d_in[1];
    const float* ea    = (const float*)d_in[2];
    const float* We    = (const float*)d_in[3];
    const float* be    = (const float*)d_in[4];
    const float* W1    = (const float*)d_in[5];
    const float* b1    = (const float*)d_in[6];
    const float* W2    = (const float*)d_in[7];
    const float* b2    = (const float*)d_in[8];
    const float* gamma = (const float*)d_in[9];
    const float* beta  = (const float*)d_in[10];
    float* out = (float*)d_out;

    char* wsp = (char*)d_ws;
    const size_t NH = (size_t)N_NODES * HIDDEN;
    float* h      = (float*)wsp;  wsp += NH * 4;                       // 25.6 MB
    float* z      = (float*)wsp;  wsp += NH * 4;                       // 25.6 MB
    u16*   ea_perm= (u16*)wsp;    wsp += (size_t)N_EDGES * EDGE_DIM * 2; // 51.2 MB
    float* stats  = (float*)wsp;  wsp += 256 * 4;
    u32*   deg    = (u32*)wsp;    wsp += (size_t)N_NODES * 4;
    u32*   cursor = (u32*)wsp;    wsp += (size_t)N_NODES * 4;
    int*   ssrc   = (int*)wsp;    wsp += (size_t)N_EDGES * 4;
    int*   seid   = (int*)wsp;    wsp += (size_t)N_EDGES * 4;
    u32*   off    = (u32*)wsp;    wsp += ((size_t)(N_NODES + 1) * 4 + 12) & ~15ull;
    size_t need_perm = (size_t)(wsp - (char*)d_ws);
    int use_perm = ws_size >= need_perm;

    const int nh_blocks = (N_NODES * HIDDEN + 255) / 256;   // 25000
    const int e_blocks  = (N_EDGES + 255) / 256;            // 3125
    const int ep_blocks = (N_EDGES * EDGE_DIM + 255) / 256; // 100000
    const int g_blocks  = (N_NODES + 31) / 32;              // 1563

    // CSR build (once per call)
    init_kernel<<<nh_blocks, 256, 0, stream>>>(x, h, deg);
    hist_kernel<<<e_blocks, 256, 0, stream>>>(ei, deg);
    scan_kernel<<<1, SCAN_THREADS, 0, stream>>>(deg, off, cursor);
    scatter_kernel<<<e_blocks, 256, 0, stream>>>(ei, cursor, ssrc, seid);
    if (use_perm)
        perm_ea_kernel<<<ep_blocks, 256, 0, stream>>>(ea, seid, ea_perm);

    for (int l = 0; l < NUM_LAYERS; l++) {
        if (use_perm)
            agg_perm_kernel<<<8192, 256, 0, stream>>>(
                h, ea_perm, ssrc, off,
                We + (size_t)l * EDGE_DIM * HIDDEN, be + (size_t)l * HIDDEN, z);
        else
            agg_ind_kernel<<<8192, 256, 0, stream>>>(
                h, ea, ssrc, seid, off,
                We + (size_t)l * EDGE_DIM * HIDDEN, be + (size_t)l * HIDDEN, z);
        gemm128_kernel<1, 0><<<g_blocks, 256, 0, stream>>>(
            z, W1 + (size_t)l * HIDDEN * HIDDEN, b1 + (size_t)l * HIDDEN, z, nullptr);
        zero_stats_kernel<<<1, 256, 0, stream>>>(stats);
        gemm128_kernel<0, 1><<<g_blocks, 256, 0, stream>>>(
            z, W2 + (size_t)l * HIDDEN * HIDDEN, b2 + (size_t)l * HIDDEN, z, stats);
        bn_kernel<<<nh_blocks, 256, 0, stream>>>(
            z, stats, gamma + (size_t)l * HIDDEN, beta + (size_t)l * HIDDEN,
            h, out, (l == NUM_LAYERS - 1) ? 1 : 0);
    }
}

// Round 5
// 1482.518 us; speedup vs baseline: 1.7445x; 1.0103x over previous
//
#include <hip/hip_runtime.h>
#include <hip/hip_bf16.h>

#define N_NODES   50000
#define N_EDGES   800000
#define IN_DIM    128
#define EDGE_DIM  32
#define HIDDEN    128
#define NUM_LAYERS 3
#define BN_EPS    1e-5f
#define RES_SCALE 0.1f

typedef unsigned int   u32;
typedef unsigned short u16;
typedef _Float16 half2_t __attribute__((ext_vector_type(2)));

__device__ __forceinline__ half2_t as_half2(u32 v) {
    union { u32 u; half2_t h; } c; c.u = v; return c.h;
}

// ---------------- copy x -> h ; zero deg ----------------
__global__ __launch_bounds__(256) void init_kernel(const float* __restrict__ x,
                                                   float* __restrict__ h,
                                                   u32* __restrict__ deg) {
    int idx = blockIdx.x * 256 + threadIdx.x;
    if (idx < N_NODES * HIDDEN) h[idx] = x[idx];
    if (idx < N_NODES) deg[idx] = 0u;
}

// ---------------- degree histogram ----------------
__global__ __launch_bounds__(256) void hist_kernel(const int* __restrict__ ei,
                                                   u32* __restrict__ deg) {
    int e = blockIdx.x * 256 + threadIdx.x;
    if (e < N_EDGES) atomicAdd(&deg[ei[N_EDGES + e]], 1u);
}

// ---------------- exclusive scan (single block) ----------------
#define SCAN_THREADS 1024
__global__ __launch_bounds__(SCAN_THREADS) void scan_kernel(
    const u32* __restrict__ deg, u32* __restrict__ off, u32* __restrict__ cursor) {
    __shared__ u32 part[SCAN_THREADS];
    int t = threadIdx.x;
    const int CHUNK = (N_NODES + SCAN_THREADS - 1) / SCAN_THREADS;  // 49
    int start = t * CHUNK;
    int end = start + CHUNK; if (end > N_NODES) end = N_NODES;
    u32 s = 0;
    for (int i = start; i < end; i++) s += deg[i];
    part[t] = s;
    __syncthreads();
    for (int d = 1; d < SCAN_THREADS; d <<= 1) {
        u32 v = (t >= d) ? part[t - d] : 0u;
        __syncthreads();
        part[t] += v;
        __syncthreads();
    }
    u32 run = (t == 0) ? 0u : part[t - 1];
    for (int i = start; i < end; i++) {
        u32 d = deg[i];
        off[i] = run;
        cursor[i] = run;
        run += d;
    }
    if (t == SCAN_THREADS - 1) off[N_NODES] = run;
}

// ---------------- scatter edges into CSR order ----------------
__global__ __launch_bounds__(256) void scatter_kernel(const int* __restrict__ ei,
                                                      u32* __restrict__ cursor,
                                                      int* __restrict__ ssrc,
                                                      int* __restrict__ seid) {
    int e = blockIdx.x * 256 + threadIdx.x;
    if (e < N_EDGES) {
        int dst = ei[N_EDGES + e];
        u32 pos = atomicAdd(&cursor[dst], 1u);
        ssrc[pos] = ei[e];
        seid[pos] = e;
    }
}

// ---------------- permute edge_attr into CSR order, cast f16 ----------------
__global__ __launch_bounds__(256) void perm_ea_kernel(const float* __restrict__ ea,
                                                      const int* __restrict__ seid,
                                                      _Float16* __restrict__ ea_perm) {
    int idx = blockIdx.x * 256 + threadIdx.x;
    if (idx < N_EDGES * EDGE_DIM) {
        int pos = idx >> 5, col = idx & 31;
        int eid = seid[pos];
        ea_perm[idx] = (_Float16)ea[(size_t)eid * EDGE_DIM + col];
    }
}

#if defined(__has_builtin)
#if __has_builtin(__builtin_amdgcn_fdot2)
#define HAVE_FDOT2 1
#endif
#endif

// f16 row (4 x uint4 = 32 halves) dot wc2[16] (half2), two fp32 chains
__device__ __forceinline__ float edot_f16(const uint4* __restrict__ p,
                                          const half2_t* __restrict__ wc2) {
    float a = 0.f, b = 0.f;
#pragma unroll
    for (int q = 0; q < 4; q++) {
        uint4 d = p[q];
#ifdef HAVE_FDOT2
        a = __builtin_amdgcn_fdot2(as_half2(d.x), wc2[q * 4 + 0], a, false);
        b = __builtin_amdgcn_fdot2(as_half2(d.y), wc2[q * 4 + 1], b, false);
        a = __builtin_amdgcn_fdot2(as_half2(d.z), wc2[q * 4 + 2], a, false);
        b = __builtin_amdgcn_fdot2(as_half2(d.w), wc2[q * 4 + 3], b, false);
#else
        half2_t h0 = as_half2(d.x), h1 = as_half2(d.y);
        half2_t h2 = as_half2(d.z), h3 = as_half2(d.w);
        a = fmaf((float)h0.x, (float)wc2[q*4+0].x, a); a = fmaf((float)h0.y, (float)wc2[q*4+0].y, a);
        b = fmaf((float)h1.x, (float)wc2[q*4+1].x, b); b = fmaf((float)h1.y, (float)wc2[q*4+1].y, b);
        a = fmaf((float)h2.x, (float)wc2[q*4+2].x, a); a = fmaf((float)h2.y, (float)wc2[q*4+2].y, a);
        b = fmaf((float)h3.x, (float)wc2[q*4+3].x, b); b = fmaf((float)h3.y, (float)wc2[q*4+3].y, b);
#endif
    }
    return a + b;
}

// ---------------- CSR aggregation (permuted f16 ea, v_dot2) ----------------
// z[n] = h[n] + sum_{e in [off[n],off[n+1])} relu(h[ssrc[e]] + ea_perm[e]@We + be)
__global__ __launch_bounds__(256) void agg_perm_kernel(
    const float* __restrict__ h, const _Float16* __restrict__ ea_perm,
    const int* __restrict__ ssrc, const u32* __restrict__ off,
    const float* __restrict__ We, const float* __restrict__ be,
    float* __restrict__ z) {
    int t = threadIdx.x;
    int f = t & 127;
    int slot = t >> 7;
    half2_t wc2[16];
#pragma unroll
    for (int k = 0; k < 16; k++) {
        half2_t w;
        w.x = (_Float16)We[(2 * k + 0) * HIDDEN + f];
        w.y = (_Float16)We[(2 * k + 1) * HIDDEN + f];
        wc2[k] = w;
    }
    float bias = be[f];
    int nslots = gridDim.x * 2;
    for (int n = blockIdx.x * 2 + slot; n < N_NODES; n += nslots) {
        int e0 = (int)off[n], e1 = (int)off[n + 1];
        float acc0 = 0.f, acc1 = 0.f;
        int e = e0;
        for (; e + 2 <= e1; e += 2) {
            int s0 = ssrc[e], s1 = ssrc[e + 1];
            const uint4* p0 = (const uint4*)(ea_perm + e * EDGE_DIM);
            float h0 = h[s0 * HIDDEN + f];
            float h1 = h[s1 * HIDDEN + f];
            float m0 = edot_f16(p0, wc2) + bias + h0;
            float m1 = edot_f16(p0 + 4, wc2) + bias + h1;
            acc0 += fmaxf(m0, 0.f);
            acc1 += fmaxf(m1, 0.f);
        }
        if (e < e1) {
            int s0 = ssrc[e];
            const uint4* p0 = (const uint4*)(ea_perm + e * EDGE_DIM);
            float m0 = edot_f16(p0, wc2) + bias + h[s0 * HIDDEN + f];
            acc0 += fmaxf(m0, 0.f);
        }
        z[n * HIDDEN + f] = h[n * HIDDEN + f] + acc0 + acc1;
    }
}

// ---------------- fallback: CSR aggregation with fp32 ea indirection ----------------
__device__ __forceinline__ float edot_f32(const float4* __restrict__ p,
                                          const float* __restrict__ wcol) {
    float ma = 0.f, mb = 0.f;
#pragma unroll
    for (int q = 0; q < 8; q++) {
        float4 v = p[q];
        if (q & 1) {
            mb = fmaf(v.x, wcol[q * 4 + 0], mb);
            mb = fmaf(v.y, wcol[q * 4 + 1], mb);
            mb = fmaf(v.z, wcol[q * 4 + 2], mb);
            mb = fmaf(v.w, wcol[q * 4 + 3], mb);
        } else {
            ma = fmaf(v.x, wcol[q * 4 + 0], ma);
            ma = fmaf(v.y, wcol[q * 4 + 1], ma);
            ma = fmaf(v.z, wcol[q * 4 + 2], ma);
            ma = fmaf(v.w, wcol[q * 4 + 3], ma);
        }
    }
    return ma + mb;
}

__global__ __launch_bounds__(256) void agg_ind_kernel(
    const float* __restrict__ h, const float* __restrict__ ea,
    const int* __restrict__ ssrc, const int* __restrict__ seid,
    const u32* __restrict__ off, const float* __restrict__ We,
    const float* __restrict__ be, float* __restrict__ z) {
    int t = threadIdx.x;
    int f = t & 127;
    int slot = t >> 7;
    float wcol[EDGE_DIM];
#pragma unroll
    for (int k = 0; k < EDGE_DIM; k++) wcol[k] = We[k * HIDDEN + f];
    float bias = be[f];
    int nslots = gridDim.x * 2;
    for (int n = blockIdx.x * 2 + slot; n < N_NODES; n += nslots) {
        int e0 = (int)off[n], e1 = (int)off[n + 1];
        float acc0 = 0.f, acc1 = 0.f;
        int e = e0;
        for (; e + 2 <= e1; e += 2) {
            int s0 = ssrc[e], s1 = ssrc[e + 1];
            int i0 = seid[e], i1 = seid[e + 1];
            const float4* p0 = (const float4*)(ea + (size_t)i0 * EDGE_DIM);
            const float4* p1 = (const float4*)(ea + (size_t)i1 * EDGE_DIM);
            float h0 = h[s0 * HIDDEN + f];
            float h1 = h[s1 * HIDDEN + f];
            float m0 = edot_f32(p0, wcol) + bias + h0;
            float m1 = edot_f32(p1, wcol) + bias + h1;
            acc0 += fmaxf(m0, 0.f);
            acc1 += fmaxf(m1, 0.f);
        }
        if (e < e1) {
            int s0 = ssrc[e];
            int i0 = seid[e];
            const float4* p0 = (const float4*)(ea + (size_t)i0 * EDGE_DIM);
            float m0 = edot_f32(p0, wcol) + bias + h[s0 * HIDDEN + f];
            acc0 += fmaxf(m0, 0.f);
        }
        z[n * HIDDEN + f] = h[n * HIDDEN + f] + acc0 + acc1;
    }
}

// ---------------- zero stats ----------------
__global__ __launch_bounds__(256) void zero_stats_kernel(float* __restrict__ stats) {
    stats[threadIdx.x] = 0.f;
}

// ---------------- 128-wide node GEMM, K-tiled, in-place safe ----------------
template <int RELU, int STATS>
__global__ __launch_bounds__(256) void gemm128_kernel(
    const float* __restrict__ in, const float* __restrict__ W,
    const float* __restrict__ bias, float* __restrict__ out,
    float* __restrict__ stats) {
    __shared__ float Wt[32][HIDDEN];        // 16 KB
    __shared__ float zt[32][33];            // 4.3 KB
    __shared__ float red[8][32][4][2];      // 8 KB
    int t = threadIdx.x;
    int base = blockIdx.x * 32;
    int ng = t >> 5, fg = t & 31;

    float acc[4][4];
#pragma unroll
    for (int i = 0; i < 4; i++)
#pragma unroll
        for (int j = 0; j < 4; j++) acc[i][j] = 0.f;

    for (int kt = 0; kt < 4; kt++) {
        int k0 = kt * 32;
        for (int i = t; i < 32 * HIDDEN; i += 256) {
            int kk = i >> 7, ff = i & 127;
            Wt[kk][ff] = W[(k0 + kk) * HIDDEN + ff];
        }
        for (int i = t; i < 32 * 32; i += 256) {
            int n = i >> 5, kk = i & 31;
            int gn = base + n;
            zt[n][kk] = (gn < N_NODES) ? in[gn * HIDDEN + k0 + kk] : 0.f;
        }
        __syncthreads();
#pragma unroll 4
        for (int kk = 0; kk < 32; kk++) {
            float zv[4];
#pragma unroll
            for (int i = 0; i < 4; i++) zv[i] = zt[ng * 4 + i][kk];
            float4 wv = *(const float4*)&Wt[kk][fg * 4];
#pragma unroll
            for (int i = 0; i < 4; i++) {
                acc[i][0] = fmaf(zv[i], wv.x, acc[i][0]);
                acc[i][1] = fmaf(zv[i], wv.y, acc[i][1]);
                acc[i][2] = fmaf(zv[i], wv.z, acc[i][2]);
                acc[i][3] = fmaf(zv[i], wv.w, acc[i][3]);
            }
        }
        __syncthreads();
    }

    float bv[4];
#pragma unroll
    for (int j = 0; j < 4; j++) bv[j] = bias[fg * 4 + j];
#pragma unroll
    for (int i = 0; i < 4; i++) {
        int gn = base + ng * 4 + i;
#pragma unroll
        for (int j = 0; j < 4; j++) {
            float v = acc[i][j] + bv[j];
            if (RELU) v = fmaxf(v, 0.f);
            acc[i][j] = v;
        }
        if (gn < N_NODES) {
            float4 st = make_float4(acc[i][0], acc[i][1], acc[i][2], acc[i][3]);
            *(float4*)&out[gn * HIDDEN + fg * 4] = st;
        }
    }

    if (STATS) {
        float s[4] = {0.f, 0.f, 0.f, 0.f}, sq[4] = {0.f, 0.f, 0.f, 0.f};
#pragma unroll
        for (int i = 0; i < 4; i++) {
            int gn = base + ng * 4 + i;
            if (gn < N_NODES) {
#pragma unroll
                for (int j = 0; j < 4; j++) {
                    s[j] += acc[i][j];
                    sq[j] = fmaf(acc[i][j], acc[i][j], sq[j]);
                }
            }
        }
#pragma unroll
        for (int j = 0; j < 4; j++) {
            red[ng][fg][j][0] = s[j];
            red[ng][fg][j][1] = sq[j];
        }
        __syncthreads();
        if (t < HIDDEN) {
            int ffg = t >> 2, jj = t & 3;
            float ts = 0.f, tq = 0.f;
            for (int g = 0; g < 8; g++) {
                ts += red[g][ffg][jj][0];
                tq += red[g][ffg][jj][1];
            }
            unsafeAtomicAdd(&stats[ffg * 4 + jj], ts);
            unsafeAtomicAdd(&stats[HIDDEN + ffg * 4 + jj], tq);
        }
    }
}

// ---------------- batchnorm + relu + residual ----------------
__global__ __launch_bounds__(256) void bn_kernel(
    const float* __restrict__ z2, const float* __restrict__ stats,
    const float* __restrict__ gamma, const float* __restrict__ beta,
    float* __restrict__ h, float* __restrict__ out, int write_out) {
    int idx = blockIdx.x * 256 + threadIdx.x;
    if (idx >= N_NODES * HIDDEN) return;
    int f = idx & 127;
    const float inv_n = 1.0f / (float)N_NODES;
    float mu = stats[f] * inv_n;
    float var = stats[HIDDEN + f] * inv_n - mu * mu;
    float inv = rsqrtf(var + BN_EPS);
    float z = (z2[idx] - mu) * inv * gamma[f] + beta[f];
    z = fmaxf(z, 0.f);
    float hn = fmaf(RES_SCALE, h[idx], z);
    h[idx] = hn;
    if (write_out) out[idx] = hn;
}

extern "C" void kernel_launch(void* const* d_in, const int* in_sizes, int n_in,
                              void* d_out, int out_size, void* d_ws, size_t ws_size,
                              hipStream_t stream) {
    const float* x     = (const float*)d_in[0];
    const int*   ei    = (const int*)d_in[1];
    const float* ea    = (const float*)d_in[2];
    const float* We    = (const float*)d_in[3];
    const float* be    = (const float*)d_in[4];
    const float* W1    = (const float*)d_in[5];
    const float* b1    = (const float*)d_in[6];
    const float* W2    = (const float*)d_in[7];
    const float* b2    = (const float*)d_in[8];
    const float* gamma = (const float*)d_in[9];
    const float* beta  = (const float*)d_in[10];
    float* out = (float*)d_out;

    char* wsp = (char*)d_ws;
    const size_t NH = (size_t)N_NODES * HIDDEN;
    float*    h      = (float*)wsp;    wsp += NH * 4;                          // 25.6 MB
    float*    z      = (float*)wsp;    wsp += NH * 4;                          // 25.6 MB
    _Float16* ea_perm= (_Float16*)wsp; wsp += (size_t)N_EDGES * EDGE_DIM * 2;  // 51.2 MB
    float*    stats  = (float*)wsp;    wsp += 256 * 4;
    u32*      deg    = (u32*)wsp;      wsp += (size_t)N_NODES * 4;
    u32*      cursor = (u32*)wsp;      wsp += (size_t)N_NODES * 4;
    int*      ssrc   = (int*)wsp;      wsp += (size_t)N_EDGES * 4;
    int*      seid   = (int*)wsp;      wsp += (size_t)N_EDGES * 4;
    u32*      off    = (u32*)wsp;      wsp += ((size_t)(N_NODES + 1) * 4 + 12) & ~15ull;
    size_t need_perm = (size_t)(wsp - (char*)d_ws);
    int use_perm = ws_size >= need_perm;

    const int nh_blocks = (N_NODES * HIDDEN + 255) / 256;   // 25000
    const int e_blocks  = (N_EDGES + 255) / 256;            // 3125
    const int ep_blocks = (N_EDGES * EDGE_DIM + 255) / 256; // 100000
    const int g_blocks  = (N_NODES + 31) / 32;              // 1563

    // CSR build (once per call)
    init_kernel<<<nh_blocks, 256, 0, stream>>>(x, h, deg);
    hist_kernel<<<e_blocks, 256, 0, stream>>>(ei, deg);
    scan_kernel<<<1, SCAN_THREADS, 0, stream>>>(deg, off, cursor);
    scatter_kernel<<<e_blocks, 256, 0, stream>>>(ei, cursor, ssrc, seid);
    if (use_perm)
        perm_ea_kernel<<<ep_blocks, 256, 0, stream>>>(ea, seid, ea_perm);

    for (int l = 0; l < NUM_LAYERS; l++) {
        if (use_perm)
            agg_perm_kernel<<<8192, 256, 0, stream>>>(
                h, ea_perm, ssrc, off,
                We + (size_t)l * EDGE_DIM * HIDDEN, be + (size_t)l * HIDDEN, z);
        else
            agg_ind_kernel<<<8192, 256, 0, stream>>>(
                h, ea, ssrc, seid, off,
                We + (size_t)l * EDGE_DIM * HIDDEN, be + (size_t)l * HIDDEN, z);
        gemm128_kernel<1, 0><<<g_blocks, 256, 0, stream>>>(
            z, W1 + (size_t)l * HIDDEN * HIDDEN, b1 + (size_t)l * HIDDEN, z, nullptr);
        zero_stats_kernel<<<1, 256, 0, stream>>>(stats);
        gemm128_kernel<0, 1><<<g_blocks, 256, 0, stream>>>(
            z, W2 + (size_t)l * HIDDEN * HIDDEN, b2 + (size_t)l * HIDDEN, z, stats);
        bn_kernel<<<nh_blocks, 256, 0, stream>>>(
            z, stats, gamma + (size_t)l * HIDDEN, beta + (size_t)l * HIDDEN,
            h, out, (l == NUM_LAYERS - 1) ? 1 : 0);
    }
}

// Round 6
// 1179.546 us; speedup vs baseline: 2.1925x; 1.2569x over previous
//
#include <hip/hip_runtime.h>
#include <hip/hip_bf16.h>

#define N_NODES   50000
#define N_EDGES   800000
#define IN_DIM    128
#define EDGE_DIM  32
#define HIDDEN    128
#define NUM_LAYERS 3
#define BN_EPS    1e-5f
#define RES_SCALE 0.1f

typedef unsigned int   u32;
typedef unsigned short u16;
typedef _Float16 half2_t __attribute__((ext_vector_type(2)));

__device__ __forceinline__ half2_t as_half2(u32 v) {
    union { u32 u; half2_t h; } c; c.u = v; return c.h;
}
__device__ __forceinline__ u32 pack_half2(float a, float b) {
    union { u32 u; half2_t h; } c;
    c.h.x = (_Float16)a; c.h.y = (_Float16)b; return c.u;
}

#if defined(__has_builtin)
#if __has_builtin(__builtin_amdgcn_fdot2)
#define HAVE_FDOT2 1
#endif
#endif

__device__ __forceinline__ float fdot2f(half2_t a, half2_t b, float c) {
#ifdef HAVE_FDOT2
    return __builtin_amdgcn_fdot2(a, b, c, false);
#else
    c = fmaf((float)a.x, (float)b.x, c);
    c = fmaf((float)a.y, (float)b.y, c);
    return c;
#endif
}

// ---------------- pack x -> h16 ; zero deg ----------------
// h16[n*64 + l] = (f16(x[n][l]), f16(x[n][l+64]))
__global__ __launch_bounds__(256) void init_kernel(const float* __restrict__ x,
                                                   u32* __restrict__ h16,
                                                   u32* __restrict__ deg) {
    int idx = blockIdx.x * 256 + threadIdx.x;
    if (idx < N_NODES * 64) {
        int n = idx >> 6, l = idx & 63;
        float a = x[n * HIDDEN + l];
        float b = x[n * HIDDEN + 64 + l];
        h16[idx] = pack_half2(a, b);
    }
    if (idx < N_NODES) deg[idx] = 0u;
}

// ---------------- degree histogram ----------------
__global__ __launch_bounds__(256) void hist_kernel(const int* __restrict__ ei,
                                                   u32* __restrict__ deg) {
    int e = blockIdx.x * 256 + threadIdx.x;
    if (e < N_EDGES) atomicAdd(&deg[ei[N_EDGES + e]], 1u);
}

// ---------------- exclusive scan (single block) ----------------
#define SCAN_THREADS 1024
__global__ __launch_bounds__(SCAN_THREADS) void scan_kernel(
    const u32* __restrict__ deg, u32* __restrict__ off, u32* __restrict__ cursor) {
    __shared__ u32 part[SCAN_THREADS];
    int t = threadIdx.x;
    const int CHUNK = (N_NODES + SCAN_THREADS - 1) / SCAN_THREADS;  // 49
    int start = t * CHUNK;
    int end = start + CHUNK; if (end > N_NODES) end = N_NODES;
    u32 s = 0;
    for (int i = start; i < end; i++) s += deg[i];
    part[t] = s;
    __syncthreads();
    for (int d = 1; d < SCAN_THREADS; d <<= 1) {
        u32 v = (t >= d) ? part[t - d] : 0u;
        __syncthreads();
        part[t] += v;
        __syncthreads();
    }
    u32 run = (t == 0) ? 0u : part[t - 1];
    for (int i = start; i < end; i++) {
        u32 d = deg[i];
        off[i] = run;
        cursor[i] = run;
        run += d;
    }
    if (t == SCAN_THREADS - 1) off[N_NODES] = run;
}

// ---------------- scatter edges into CSR order ----------------
__global__ __launch_bounds__(256) void scatter_kernel(const int* __restrict__ ei,
                                                      u32* __restrict__ cursor,
                                                      int* __restrict__ ssrc,
                                                      int* __restrict__ seid) {
    int e = blockIdx.x * 256 + threadIdx.x;
    if (e < N_EDGES) {
        int dst = ei[N_EDGES + e];
        u32 pos = atomicAdd(&cursor[dst], 1u);
        ssrc[pos] = ei[e];
        seid[pos] = e;
    }
}

// ---------------- permute edge_attr into CSR order, cast f16 ----------------
__global__ __launch_bounds__(256) void perm_ea_kernel(const float* __restrict__ ea,
                                                      const int* __restrict__ seid,
                                                      _Float16* __restrict__ ea_perm) {
    int idx = blockIdx.x * 256 + threadIdx.x;
    if (idx < N_EDGES * EDGE_DIM) {
        int pos = idx >> 5, col = idx & 31;
        int eid = seid[pos];
        ea_perm[idx] = (_Float16)ea[(size_t)eid * EDGE_DIM + col];
    }
}

// dot of one ea row (4 x uint4 = 32 halves) against wlo/whi, two fp32 accums
__device__ __forceinline__ void edot_pair(const uint4* __restrict__ p,
                                          const half2_t* __restrict__ wlo,
                                          const half2_t* __restrict__ whi,
                                          float& dl, float& dh) {
#pragma unroll
    for (int q = 0; q < 4; q++) {
        uint4 d = p[q];
        dl = fdot2f(as_half2(d.x), wlo[q * 4 + 0], dl);
        dh = fdot2f(as_half2(d.x), whi[q * 4 + 0], dh);
        dl = fdot2f(as_half2(d.y), wlo[q * 4 + 1], dl);
        dh = fdot2f(as_half2(d.y), whi[q * 4 + 1], dh);
        dl = fdot2f(as_half2(d.z), wlo[q * 4 + 2], dl);
        dh = fdot2f(as_half2(d.z), whi[q * 4 + 2], dh);
        dl = fdot2f(as_half2(d.w), wlo[q * 4 + 3], dl);
        dh = fdot2f(as_half2(d.w), whi[q * 4 + 3], dh);
    }
}

// ---------------- CSR aggregation: one WAVE per node slot ----------------
// lane owns features f=lane and f=lane+64.
// z[n][f] = h[n][f] + sum_e relu(h16[src][f] + ea_perm[e]@We[:,f] + be[f])
__global__ __launch_bounds__(256) void agg_perm_kernel(
    const u32* __restrict__ h16, const _Float16* __restrict__ ea_perm,
    const int* __restrict__ ssrc, const u32* __restrict__ off,
    const float* __restrict__ We, const float* __restrict__ be,
    float* __restrict__ z) {
    int t = threadIdx.x;
    int lane = t & 63;
    half2_t wlo[16], whi[16];
#pragma unroll
    for (int k = 0; k < 16; k++) {
        half2_t a, b;
        a.x = (_Float16)We[(2 * k + 0) * HIDDEN + lane];
        a.y = (_Float16)We[(2 * k + 1) * HIDDEN + lane];
        b.x = (_Float16)We[(2 * k + 0) * HIDDEN + 64 + lane];
        b.y = (_Float16)We[(2 * k + 1) * HIDDEN + 64 + lane];
        wlo[k] = a; whi[k] = b;
    }
    float blo = be[lane], bhi = be[64 + lane];
    int slot = blockIdx.x * 4 + (t >> 6);
    int nslots = gridDim.x * 4;
    for (int n = slot; n < N_NODES; n += nslots) {
        int e0 = (int)off[n], e1 = (int)off[n + 1];
        float al0 = 0.f, ah0 = 0.f, al1 = 0.f, ah1 = 0.f;
        int e = e0;
        for (; e + 2 <= e1; e += 2) {
            int s0 = ssrc[e], s1 = ssrc[e + 1];
            const uint4* p = (const uint4*)(ea_perm + (size_t)e * EDGE_DIM);
            u32 g0 = h16[s0 * 64 + lane];
            u32 g1 = h16[s1 * 64 + lane];
            float d0l = 0.f, d0h = 0.f, d1l = 0.f, d1h = 0.f;
            edot_pair(p, wlo, whi, d0l, d0h);
            edot_pair(p + 4, wlo, whi, d1l, d1h);
            half2_t hh0 = as_half2(g0), hh1 = as_half2(g1);
            al0 += fmaxf(d0l + blo + (float)hh0.x, 0.f);
            ah0 += fmaxf(d0h + bhi + (float)hh0.y, 0.f);
            al1 += fmaxf(d1l + blo + (float)hh1.x, 0.f);
            ah1 += fmaxf(d1h + bhi + (float)hh1.y, 0.f);
        }
        if (e < e1) {
            int s0 = ssrc[e];
            const uint4* p = (const uint4*)(ea_perm + (size_t)e * EDGE_DIM);
            float dl = 0.f, dh = 0.f;
            edot_pair(p, wlo, whi, dl, dh);
            half2_t hh = as_half2(h16[s0 * 64 + lane]);
            al0 += fmaxf(dl + blo + (float)hh.x, 0.f);
            ah0 += fmaxf(dh + bhi + (float)hh.y, 0.f);
        }
        half2_t self = as_half2(h16[n * 64 + lane]);
        z[n * HIDDEN + lane]      = (float)self.x + al0 + al1;
        z[n * HIDDEN + 64 + lane] = (float)self.y + ah0 + ah1;
    }
}

// ---------------- zero stats ----------------
__global__ __launch_bounds__(256) void zero_stats_kernel(float* __restrict__ stats) {
    stats[threadIdx.x] = 0.f;
}

// ---------------- 128-wide node GEMM, K-tiled, in-place safe ----------------
template <int RELU, int STATS>
__global__ __launch_bounds__(256) void gemm128_kernel(
    const float* __restrict__ in, const float* __restrict__ W,
    const float* __restrict__ bias, float* __restrict__ out,
    float* __restrict__ stats) {
    __shared__ float Wt[32][HIDDEN];        // 16 KB
    __shared__ float zt[32][33];            // 4.3 KB
    __shared__ float red[8][32][4][2];      // 8 KB
    int t = threadIdx.x;
    int base = blockIdx.x * 32;
    int ng = t >> 5, fg = t & 31;

    float acc[4][4];
#pragma unroll
    for (int i = 0; i < 4; i++)
#pragma unroll
        for (int j = 0; j < 4; j++) acc[i][j] = 0.f;

    for (int kt = 0; kt < 4; kt++) {
        int k0 = kt * 32;
        for (int i = t; i < 32 * HIDDEN; i += 256) {
            int kk = i >> 7, ff = i & 127;
            Wt[kk][ff] = W[(k0 + kk) * HIDDEN + ff];
        }
        for (int i = t; i < 32 * 32; i += 256) {
            int n = i >> 5, kk = i & 31;
            int gn = base + n;
            zt[n][kk] = (gn < N_NODES) ? in[gn * HIDDEN + k0 + kk] : 0.f;
        }
        __syncthreads();
#pragma unroll 4
        for (int kk = 0; kk < 32; kk++) {
            float zv[4];
#pragma unroll
            for (int i = 0; i < 4; i++) zv[i] = zt[ng * 4 + i][kk];
            float4 wv = *(const float4*)&Wt[kk][fg * 4];
#pragma unroll
            for (int i = 0; i < 4; i++) {
                acc[i][0] = fmaf(zv[i], wv.x, acc[i][0]);
                acc[i][1] = fmaf(zv[i], wv.y, acc[i][1]);
                acc[i][2] = fmaf(zv[i], wv.z, acc[i][2]);
                acc[i][3] = fmaf(zv[i], wv.w, acc[i][3]);
            }
        }
        __syncthreads();
    }

    float bv[4];
#pragma unroll
    for (int j = 0; j < 4; j++) bv[j] = bias[fg * 4 + j];
#pragma unroll
    for (int i = 0; i < 4; i++) {
        int gn = base + ng * 4 + i;
#pragma unroll
        for (int j = 0; j < 4; j++) {
            float v = acc[i][j] + bv[j];
            if (RELU) v = fmaxf(v, 0.f);
            acc[i][j] = v;
        }
        if (gn < N_NODES) {
            float4 st = make_float4(acc[i][0], acc[i][1], acc[i][2], acc[i][3]);
            *(float4*)&out[gn * HIDDEN + fg * 4] = st;
        }
    }

    if (STATS) {
        float s[4] = {0.f, 0.f, 0.f, 0.f}, sq[4] = {0.f, 0.f, 0.f, 0.f};
#pragma unroll
        for (int i = 0; i < 4; i++) {
            int gn = base + ng * 4 + i;
            if (gn < N_NODES) {
#pragma unroll
                for (int j = 0; j < 4; j++) {
                    s[j] += acc[i][j];
                    sq[j] = fmaf(acc[i][j], acc[i][j], sq[j]);
                }
            }
        }
#pragma unroll
        for (int j = 0; j < 4; j++) {
            red[ng][fg][j][0] = s[j];
            red[ng][fg][j][1] = sq[j];
        }
        __syncthreads();
        if (t < HIDDEN) {
            int ffg = t >> 2, jj = t & 3;
            float ts = 0.f, tq = 0.f;
            for (int g = 0; g < 8; g++) {
                ts += red[g][ffg][jj][0];
                tq += red[g][ffg][jj][1];
            }
            unsafeAtomicAdd(&stats[ffg * 4 + jj], ts);
            unsafeAtomicAdd(&stats[HIDDEN + ffg * 4 + jj], tq);
        }
    }
}

// ---------------- batchnorm + relu + residual (paired features) ----------------
// one thread per (node, l in [0,64)): handles f=l and f=l+64
__global__ __launch_bounds__(256) void bn_kernel(
    const float* __restrict__ z2, const float* __restrict__ stats,
    const float* __restrict__ gamma, const float* __restrict__ beta,
    u32* __restrict__ h16, float* __restrict__ out, int write_out) {
    int idx = blockIdx.x * 256 + threadIdx.x;
    if (idx >= N_NODES * 64) return;
    int n = idx >> 6, l = idx & 63;
    const float inv_n = 1.0f / (float)N_NODES;
    float mu_l = stats[l] * inv_n;
    float mu_h = stats[64 + l] * inv_n;
    float var_l = stats[HIDDEN + l] * inv_n - mu_l * mu_l;
    float var_h = stats[HIDDEN + 64 + l] * inv_n - mu_h * mu_h;
    float inv_l = rsqrtf(var_l + BN_EPS);
    float inv_h = rsqrtf(var_h + BN_EPS);
    float zl = (z2[n * HIDDEN + l]      - mu_l) * inv_l * gamma[l]      + beta[l];
    float zh = (z2[n * HIDDEN + 64 + l] - mu_h) * inv_h * gamma[64 + l] + beta[64 + l];
    zl = fmaxf(zl, 0.f);
    zh = fmaxf(zh, 0.f);
    half2_t hh = as_half2(h16[idx]);
    float hn_l = fmaf(RES_SCALE, (float)hh.x, zl);
    float hn_h = fmaf(RES_SCALE, (float)hh.y, zh);
    h16[idx] = pack_half2(hn_l, hn_h);
    if (write_out) {
        out[n * HIDDEN + l] = hn_l;
        out[n * HIDDEN + 64 + l] = hn_h;
    }
}

extern "C" void kernel_launch(void* const* d_in, const int* in_sizes, int n_in,
                              void* d_out, int out_size, void* d_ws, size_t ws_size,
                              hipStream_t stream) {
    const float* x     = (const float*)d_in[0];
    const int*   ei    = (const int*)d_in[1];
    const float* ea    = (const float*)d_in[2];
    const float* We    = (const float*)d_in[3];
    const float* be    = (const float*)d_in[4];
    const float* W1    = (const float*)d_in[5];
    const float* b1    = (const float*)d_in[6];
    const float* W2    = (const float*)d_in[7];
    const float* b2    = (const float*)d_in[8];
    const float* gamma = (const float*)d_in[9];
    const float* beta  = (const float*)d_in[10];
    float* out = (float*)d_out;

    char* wsp = (char*)d_ws;
    const size_t NH = (size_t)N_NODES * HIDDEN;
    u32*      h16    = (u32*)wsp;      wsp += (size_t)N_NODES * 64 * 4;        // 12.8 MB
    float*    z      = (float*)wsp;    wsp += NH * 4;                          // 25.6 MB
    _Float16* ea_perm= (_Float16*)wsp; wsp += (size_t)N_EDGES * EDGE_DIM * 2;  // 51.2 MB
    float*    stats  = (float*)wsp;    wsp += 256 * 4;
    u32*      deg    = (u32*)wsp;      wsp += (size_t)N_NODES * 4;
    u32*      cursor = (u32*)wsp;      wsp += (size_t)N_NODES * 4;
    int*      ssrc   = (int*)wsp;      wsp += (size_t)N_EDGES * 4;
    int*      seid   = (int*)wsp;      wsp += (size_t)N_EDGES * 4;
    u32*      off    = (u32*)wsp;      wsp += (size_t)(N_NODES + 1) * 4;

    const int p_blocks  = (N_NODES * 64 + 255) / 256;       // 12500
    const int e_blocks  = (N_EDGES + 255) / 256;            // 3125
    const int ep_blocks = (N_EDGES * EDGE_DIM + 255) / 256; // 100000
    const int g_blocks  = (N_NODES + 31) / 32;              // 1563

    // CSR build (once per call)
    init_kernel<<<p_blocks, 256, 0, stream>>>(x, h16, deg);
    hist_kernel<<<e_blocks, 256, 0, stream>>>(ei, deg);
    scan_kernel<<<1, SCAN_THREADS, 0, stream>>>(deg, off, cursor);
    scatter_kernel<<<e_blocks, 256, 0, stream>>>(ei, cursor, ssrc, seid);
    perm_ea_kernel<<<ep_blocks, 256, 0, stream>>>(ea, seid, ea_perm);

    for (int l = 0; l < NUM_LAYERS; l++) {
        agg_perm_kernel<<<4096, 256, 0, stream>>>(
            h16, ea_perm, ssrc, off,
            We + (size_t)l * EDGE_DIM * HIDDEN, be + (size_t)l * HIDDEN, z);
        gemm128_kernel<1, 0><<<g_blocks, 256, 0, stream>>>(
            z, W1 + (size_t)l * HIDDEN * HIDDEN, b1 + (size_t)l * HIDDEN, z, nullptr);
        zero_stats_kernel<<<1, 256, 0, stream>>>(stats);
        gemm128_kernel<0, 1><<<g_blocks, 256, 0, stream>>>(
            z, W2 + (size_t)l * HIDDEN * HIDDEN, b2 + (size_t)l * HIDDEN, z, stats);
        bn_kernel<<<p_blocks, 256, 0, stream>>>(
            z, stats, gamma + (size_t)l * HIDDEN, beta + (size_t)l * HIDDEN,
            h16, out, (l == NUM_LAYERS - 1) ? 1 : 0);
    }
}

// Round 7
// 1074.599 us; speedup vs baseline: 2.4067x; 1.0977x over previous
//
#include <hip/hip_runtime.h>
#include <hip/hip_bf16.h>

#define N_NODES   50000
#define N_EDGES   800000
#define IN_DIM    128
#define EDGE_DIM  32
#define HIDDEN    128
#define NUM_LAYERS 3
#define BN_EPS    1e-5f
#define RES_SCALE 0.1f

typedef unsigned int   u32;
typedef unsigned short u16;
typedef _Float16 half2_t __attribute__((ext_vector_type(2)));

__device__ __forceinline__ half2_t as_half2(u32 v) {
    union { u32 u; half2_t h; } c; c.u = v; return c.h;
}
__device__ __forceinline__ u32 pack_half2(float a, float b) {
    union { u32 u; half2_t h; } c;
    c.h.x = (_Float16)a; c.h.y = (_Float16)b; return c.u;
}

#if defined(__has_builtin)
#if __has_builtin(__builtin_amdgcn_fdot2)
#define HAVE_FDOT2 1
#endif
#endif

__device__ __forceinline__ float fdot2f(half2_t a, half2_t b, float c) {
#ifdef HAVE_FDOT2
    return __builtin_amdgcn_fdot2(a, b, c, false);
#else
    c = fmaf((float)a.x, (float)b.x, c);
    c = fmaf((float)a.y, (float)b.y, c);
    return c;
#endif
}

// ---------------- pack x -> h16 ; zero deg ----------------
__global__ __launch_bounds__(256) void init_kernel(const float* __restrict__ x,
                                                   u32* __restrict__ h16,
                                                   u32* __restrict__ deg) {
    int idx = blockIdx.x * 256 + threadIdx.x;
    if (idx < N_NODES * 64) {
        int n = idx >> 6, l = idx & 63;
        float a = x[n * HIDDEN + l];
        float b = x[n * HIDDEN + 64 + l];
        h16[idx] = pack_half2(a, b);
    }
    if (idx < N_NODES) deg[idx] = 0u;
}

// ---------------- degree histogram ----------------
__global__ __launch_bounds__(256) void hist_kernel(const int* __restrict__ ei,
                                                   u32* __restrict__ deg) {
    int e = blockIdx.x * 256 + threadIdx.x;
    if (e < N_EDGES) atomicAdd(&deg[ei[N_EDGES + e]], 1u);
}

// ---------------- exclusive scan (single block) ----------------
#define SCAN_THREADS 1024
__global__ __launch_bounds__(SCAN_THREADS) void scan_kernel(
    const u32* __restrict__ deg, u32* __restrict__ off, u32* __restrict__ cursor) {
    __shared__ u32 part[SCAN_THREADS];
    int t = threadIdx.x;
    const int CHUNK = (N_NODES + SCAN_THREADS - 1) / SCAN_THREADS;  // 49
    int start = t * CHUNK;
    int end = start + CHUNK; if (end > N_NODES) end = N_NODES;
    u32 s = 0;
    for (int i = start; i < end; i++) s += deg[i];
    part[t] = s;
    __syncthreads();
    for (int d = 1; d < SCAN_THREADS; d <<= 1) {
        u32 v = (t >= d) ? part[t - d] : 0u;
        __syncthreads();
        part[t] += v;
        __syncthreads();
    }
    u32 run = (t == 0) ? 0u : part[t - 1];
    for (int i = start; i < end; i++) {
        u32 d = deg[i];
        off[i] = run;
        cursor[i] = run;
        run += d;
    }
    if (t == SCAN_THREADS - 1) off[N_NODES] = run;
}

// ---------------- scatter edges into CSR order + permute ea (f16) ----------------
// Sequential read of ea row, random 64-B write of converted row. No seid.
__global__ __launch_bounds__(256) void scatter_kernel(const int* __restrict__ ei,
                                                      u32* __restrict__ cursor,
                                                      int* __restrict__ ssrc,
                                                      const float* __restrict__ ea,
                                                      _Float16* __restrict__ ea_perm) {
    int e = blockIdx.x * 256 + threadIdx.x;
    if (e >= N_EDGES) return;
    int dst = ei[N_EDGES + e];
    u32 pos = atomicAdd(&cursor[dst], 1u);
    ssrc[pos] = ei[e];
    const float4* src = (const float4*)(ea + (size_t)e * EDGE_DIM);
    u32 buf[16];
#pragma unroll
    for (int q = 0; q < 8; q++) {
        float4 v = src[q];
        buf[2 * q + 0] = pack_half2(v.x, v.y);
        buf[2 * q + 1] = pack_half2(v.z, v.w);
    }
    uint4* dp = (uint4*)(ea_perm + (size_t)pos * EDGE_DIM);
#pragma unroll
    for (int q = 0; q < 4; q++)
        dp[q] = make_uint4(buf[4 * q], buf[4 * q + 1], buf[4 * q + 2], buf[4 * q + 3]);
}

// dot of one ea row (4 x uint4 = 32 halves) against wlo/whi, two fp32 accums
__device__ __forceinline__ void edot_pair(const uint4* __restrict__ p,
                                          const half2_t* __restrict__ wlo,
                                          const half2_t* __restrict__ whi,
                                          float& dl, float& dh) {
#pragma unroll
    for (int q = 0; q < 4; q++) {
        uint4 d = p[q];
        dl = fdot2f(as_half2(d.x), wlo[q * 4 + 0], dl);
        dh = fdot2f(as_half2(d.x), whi[q * 4 + 0], dh);
        dl = fdot2f(as_half2(d.y), wlo[q * 4 + 1], dl);
        dh = fdot2f(as_half2(d.y), whi[q * 4 + 1], dh);
        dl = fdot2f(as_half2(d.z), wlo[q * 4 + 2], dl);
        dh = fdot2f(as_half2(d.z), whi[q * 4 + 2], dh);
        dl = fdot2f(as_half2(d.w), wlo[q * 4 + 3], dl);
        dh = fdot2f(as_half2(d.w), whi[q * 4 + 3], dh);
    }
}

// ---------------- CSR aggregation: one WAVE per node slot, 4-edge unroll ----------------
__global__ __launch_bounds__(256) void agg_perm_kernel(
    const u32* __restrict__ h16, const _Float16* __restrict__ ea_perm,
    const int* __restrict__ ssrc, const u32* __restrict__ off,
    const float* __restrict__ We, const float* __restrict__ be,
    float* __restrict__ z) {
    int t = threadIdx.x;
    int lane = t & 63;
    half2_t wlo[16], whi[16];
#pragma unroll
    for (int k = 0; k < 16; k++) {
        half2_t a, b;
        a.x = (_Float16)We[(2 * k + 0) * HIDDEN + lane];
        a.y = (_Float16)We[(2 * k + 1) * HIDDEN + lane];
        b.x = (_Float16)We[(2 * k + 0) * HIDDEN + 64 + lane];
        b.y = (_Float16)We[(2 * k + 1) * HIDDEN + 64 + lane];
        wlo[k] = a; whi[k] = b;
    }
    float blo = be[lane], bhi = be[64 + lane];
    int slot = blockIdx.x * 4 + (t >> 6);
    int nslots = gridDim.x * 4;
    for (int n = slot; n < N_NODES; n += nslots) {
        int e0 = (int)off[n], e1 = (int)off[n + 1];
        float al0 = 0.f, ah0 = 0.f, al1 = 0.f, ah1 = 0.f;
        int e = e0;
        for (; e + 4 <= e1; e += 4) {
            int s0 = ssrc[e], s1 = ssrc[e + 1], s2 = ssrc[e + 2], s3 = ssrc[e + 3];
            const uint4* p = (const uint4*)(ea_perm + (size_t)e * EDGE_DIM);
            u32 g0 = h16[s0 * 64 + lane];
            u32 g1 = h16[s1 * 64 + lane];
            u32 g2 = h16[s2 * 64 + lane];
            u32 g3 = h16[s3 * 64 + lane];
            float d0l = 0.f, d0h = 0.f, d1l = 0.f, d1h = 0.f;
            float d2l = 0.f, d2h = 0.f, d3l = 0.f, d3h = 0.f;
            edot_pair(p,      wlo, whi, d0l, d0h);
            edot_pair(p + 4,  wlo, whi, d1l, d1h);
            edot_pair(p + 8,  wlo, whi, d2l, d2h);
            edot_pair(p + 12, wlo, whi, d3l, d3h);
            half2_t hh0 = as_half2(g0), hh1 = as_half2(g1);
            half2_t hh2 = as_half2(g2), hh3 = as_half2(g3);
            al0 += fmaxf(d0l + blo + (float)hh0.x, 0.f);
            ah0 += fmaxf(d0h + bhi + (float)hh0.y, 0.f);
            al1 += fmaxf(d1l + blo + (float)hh1.x, 0.f);
            ah1 += fmaxf(d1h + bhi + (float)hh1.y, 0.f);
            al0 += fmaxf(d2l + blo + (float)hh2.x, 0.f);
            ah0 += fmaxf(d2h + bhi + (float)hh2.y, 0.f);
            al1 += fmaxf(d3l + blo + (float)hh3.x, 0.f);
            ah1 += fmaxf(d3h + bhi + (float)hh3.y, 0.f);
        }
        for (; e + 2 <= e1; e += 2) {
            int s0 = ssrc[e], s1 = ssrc[e + 1];
            const uint4* p = (const uint4*)(ea_perm + (size_t)e * EDGE_DIM);
            u32 g0 = h16[s0 * 64 + lane];
            u32 g1 = h16[s1 * 64 + lane];
            float d0l = 0.f, d0h = 0.f, d1l = 0.f, d1h = 0.f;
            edot_pair(p,     wlo, whi, d0l, d0h);
            edot_pair(p + 4, wlo, whi, d1l, d1h);
            half2_t hh0 = as_half2(g0), hh1 = as_half2(g1);
            al0 += fmaxf(d0l + blo + (float)hh0.x, 0.f);
            ah0 += fmaxf(d0h + bhi + (float)hh0.y, 0.f);
            al1 += fmaxf(d1l + blo + (float)hh1.x, 0.f);
            ah1 += fmaxf(d1h + bhi + (float)hh1.y, 0.f);
        }
        if (e < e1) {
            int s0 = ssrc[e];
            const uint4* p = (const uint4*)(ea_perm + (size_t)e * EDGE_DIM);
            float dl = 0.f, dh = 0.f;
            edot_pair(p, wlo, whi, dl, dh);
            half2_t hh = as_half2(h16[s0 * 64 + lane]);
            al0 += fmaxf(dl + blo + (float)hh.x, 0.f);
            ah0 += fmaxf(dh + bhi + (float)hh.y, 0.f);
        }
        half2_t self = as_half2(h16[n * 64 + lane]);
        z[n * HIDDEN + lane]      = (float)self.x + al0 + al1;
        z[n * HIDDEN + 64 + lane] = (float)self.y + ah0 + ah1;
    }
}

// ---------------- zero stats ----------------
__global__ __launch_bounds__(256) void zero_stats_kernel(float* __restrict__ stats) {
    stats[threadIdx.x] = 0.f;
}

// ---------------- 128-wide node GEMM, K-tiled, in-place safe ----------------
template <int RELU, int STATS>
__global__ __launch_bounds__(256) void gemm128_kernel(
    const float* __restrict__ in, const float* __restrict__ W,
    const float* __restrict__ bias, float* __restrict__ out,
    float* __restrict__ stats) {
    __shared__ float Wt[32][HIDDEN];        // 16 KB
    __shared__ float zt[32][33];            // 4.3 KB
    __shared__ float red[8][32][4][2];      // 8 KB
    int t = threadIdx.x;
    int base = blockIdx.x * 32;
    int ng = t >> 5, fg = t & 31;

    float acc[4][4];
#pragma unroll
    for (int i = 0; i < 4; i++)
#pragma unroll
        for (int j = 0; j < 4; j++) acc[i][j] = 0.f;

    for (int kt = 0; kt < 4; kt++) {
        int k0 = kt * 32;
        for (int i = t; i < 32 * HIDDEN; i += 256) {
            int kk = i >> 7, ff = i & 127;
            Wt[kk][ff] = W[(k0 + kk) * HIDDEN + ff];
        }
        for (int i = t; i < 32 * 32; i += 256) {
            int n = i >> 5, kk = i & 31;
            int gn = base + n;
            zt[n][kk] = (gn < N_NODES) ? in[gn * HIDDEN + k0 + kk] : 0.f;
        }
        __syncthreads();
#pragma unroll 4
        for (int kk = 0; kk < 32; kk++) {
            float zv[4];
#pragma unroll
            for (int i = 0; i < 4; i++) zv[i] = zt[ng * 4 + i][kk];
            float4 wv = *(const float4*)&Wt[kk][fg * 4];
#pragma unroll
            for (int i = 0; i < 4; i++) {
                acc[i][0] = fmaf(zv[i], wv.x, acc[i][0]);
                acc[i][1] = fmaf(zv[i], wv.y, acc[i][1]);
                acc[i][2] = fmaf(zv[i], wv.z, acc[i][2]);
                acc[i][3] = fmaf(zv[i], wv.w, acc[i][3]);
            }
        }
        __syncthreads();
    }

    float bv[4];
#pragma unroll
    for (int j = 0; j < 4; j++) bv[j] = bias[fg * 4 + j];
#pragma unroll
    for (int i = 0; i < 4; i++) {
        int gn = base + ng * 4 + i;
#pragma unroll
        for (int j = 0; j < 4; j++) {
            float v = acc[i][j] + bv[j];
            if (RELU) v = fmaxf(v, 0.f);
            acc[i][j] = v;
        }
        if (gn < N_NODES) {
            float4 st = make_float4(acc[i][0], acc[i][1], acc[i][2], acc[i][3]);
            *(float4*)&out[gn * HIDDEN + fg * 4] = st;
        }
    }

    if (STATS) {
        float s[4] = {0.f, 0.f, 0.f, 0.f}, sq[4] = {0.f, 0.f, 0.f, 0.f};
#pragma unroll
        for (int i = 0; i < 4; i++) {
            int gn = base + ng * 4 + i;
            if (gn < N_NODES) {
#pragma unroll
                for (int j = 0; j < 4; j++) {
                    s[j] += acc[i][j];
                    sq[j] = fmaf(acc[i][j], acc[i][j], sq[j]);
                }
            }
        }
#pragma unroll
        for (int j = 0; j < 4; j++) {
            red[ng][fg][j][0] = s[j];
            red[ng][fg][j][1] = sq[j];
        }
        __syncthreads();
        if (t < HIDDEN) {
            int ffg = t >> 2, jj = t & 3;
            float ts = 0.f, tq = 0.f;
            for (int g = 0; g < 8; g++) {
                ts += red[g][ffg][jj][0];
                tq += red[g][ffg][jj][1];
            }
            unsafeAtomicAdd(&stats[ffg * 4 + jj], ts);
            unsafeAtomicAdd(&stats[HIDDEN + ffg * 4 + jj], tq);
        }
    }
}

// ---------------- batchnorm + relu + residual (paired features) ----------------
__global__ __launch_bounds__(256) void bn_kernel(
    const float* __restrict__ z2, const float* __restrict__ stats,
    const float* __restrict__ gamma, const float* __restrict__ beta,
    u32* __restrict__ h16, float* __restrict__ out, int write_out) {
    int idx = blockIdx.x * 256 + threadIdx.x;
    if (idx >= N_NODES * 64) return;
    int n = idx >> 6, l = idx & 63;
    const float inv_n = 1.0f / (float)N_NODES;
    float mu_l = stats[l] * inv_n;
    float mu_h = stats[64 + l] * inv_n;
    float var_l = stats[HIDDEN + l] * inv_n - mu_l * mu_l;
    float var_h = stats[HIDDEN + 64 + l] * inv_n - mu_h * mu_h;
    float inv_l = rsqrtf(var_l + BN_EPS);
    float inv_h = rsqrtf(var_h + BN_EPS);
    float zl = (z2[n * HIDDEN + l]      - mu_l) * inv_l * gamma[l]      + beta[l];
    float zh = (z2[n * HIDDEN + 64 + l] - mu_h) * inv_h * gamma[64 + l] + beta[64 + l];
    zl = fmaxf(zl, 0.f);
    zh = fmaxf(zh, 0.f);
    half2_t hh = as_half2(h16[idx]);
    float hn_l = fmaf(RES_SCALE, (float)hh.x, zl);
    float hn_h = fmaf(RES_SCALE, (float)hh.y, zh);
    h16[idx] = pack_half2(hn_l, hn_h);
    if (write_out) {
        out[n * HIDDEN + l] = hn_l;
        out[n * HIDDEN + 64 + l] = hn_h;
    }
}

extern "C" void kernel_launch(void* const* d_in, const int* in_sizes, int n_in,
                              void* d_out, int out_size, void* d_ws, size_t ws_size,
                              hipStream_t stream) {
    const float* x     = (const float*)d_in[0];
    const int*   ei    = (const int*)d_in[1];
    const float* ea    = (const float*)d_in[2];
    const float* We    = (const float*)d_in[3];
    const float* be    = (const float*)d_in[4];
    const float* W1    = (const float*)d_in[5];
    const float* b1    = (const float*)d_in[6];
    const float* W2    = (const float*)d_in[7];
    const float* b2    = (const float*)d_in[8];
    const float* gamma = (const float*)d_in[9];
    const float* beta  = (const float*)d_in[10];
    float* out = (float*)d_out;

    char* wsp = (char*)d_ws;
    const size_t NH = (size_t)N_NODES * HIDDEN;
    u32*      h16    = (u32*)wsp;      wsp += (size_t)N_NODES * 64 * 4;        // 12.8 MB
    float*    z      = (float*)wsp;    wsp += NH * 4;                          // 25.6 MB
    _Float16* ea_perm= (_Float16*)wsp; wsp += (size_t)N_EDGES * EDGE_DIM * 2;  // 51.2 MB
    float*    stats  = (float*)wsp;    wsp += 256 * 4;
    u32*      deg    = (u32*)wsp;      wsp += (size_t)N_NODES * 4;
    u32*      cursor = (u32*)wsp;      wsp += (size_t)N_NODES * 4;
    int*      ssrc   = (int*)wsp;      wsp += (size_t)N_EDGES * 4;
    u32*      off    = (u32*)wsp;      wsp += (size_t)(N_NODES + 1) * 4;

    const int p_blocks  = (N_NODES * 64 + 255) / 256;       // 12500
    const int e_blocks  = (N_EDGES + 255) / 256;            // 3125
    const int g_blocks  = (N_NODES + 31) / 32;              // 1563

    // CSR build (once per call)
    init_kernel<<<p_blocks, 256, 0, stream>>>(x, h16, deg);
    hist_kernel<<<e_blocks, 256, 0, stream>>>(ei, deg);
    scan_kernel<<<1, SCAN_THREADS, 0, stream>>>(deg, off, cursor);
    scatter_kernel<<<e_blocks, 256, 0, stream>>>(ei, cursor, ssrc, ea, ea_perm);

    for (int l = 0; l < NUM_LAYERS; l++) {
        agg_perm_kernel<<<4096, 256, 0, stream>>>(
            h16, ea_perm, ssrc, off,
            We + (size_t)l * EDGE_DIM * HIDDEN, be + (size_t)l * HIDDEN, z);
        gemm128_kernel<1, 0><<<g_blocks, 256, 0, stream>>>(
            z, W1 + (size_t)l * HIDDEN * HIDDEN, b1 + (size_t)l * HIDDEN, z, nullptr);
        zero_stats_kernel<<<1, 256, 0, stream>>>(stats);
        gemm128_kernel<0, 1><<<g_blocks, 256, 0, stream>>>(
            z, W2 + (size_t)l * HIDDEN * HIDDEN, b2 + (size_t)l * HIDDEN, z, stats);
        bn_kernel<<<p_blocks, 256, 0, stream>>>(
            z, stats, gamma + (size_t)l * HIDDEN, beta + (size_t)l * HIDDEN,
            h16, out, (l == NUM_LAYERS - 1) ? 1 : 0);
    }
}